// Round 17
// baseline (300.513 us; speedup 1.0000x reference)
//
#include <hip/hip_runtime.h>
#include <stdint.h>

typedef unsigned short u16;
typedef short bf16x8 __attribute__((ext_vector_type(8)));
typedef float f32x4 __attribute__((ext_vector_type(4)));
typedef u16 u16x8 __attribute__((ext_vector_type(8)));
typedef u16 u16x4 __attribute__((ext_vector_type(4)));
typedef uint32_t u32x4 __attribute__((ext_vector_type(4)));
typedef uint32_t u32x2 __attribute__((ext_vector_type(2)));

typedef const __attribute__((address_space(1))) void gvoid_t;
typedef __attribute__((address_space(3))) void lvoid_t;

__device__ __forceinline__ u16 f2bf(float f) {
  uint32_t u = __float_as_uint(f);
  return (u16)((u + 0x7fffu + ((u >> 16) & 1u)) >> 16);
}

__device__ __forceinline__ uint32_t cvtpk(float a, float b) {
  uint32_t r;
  asm("v_cvt_pk_bf16_f32 %0, %1, %2" : "=v"(r) : "v"(a), "v"(b));
  return r;  // lo16 = bf16(a), hi16 = bf16(b)
}

__device__ __forceinline__ void gload16(const void* g, void* l) {
  __builtin_amdgcn_global_load_lds((gvoid_t*)g, (lvoid_t*)l, 16, 0, 0);
}

// ---------------------------------------------------------------- weights cast
// Wcat[1536][256] = [Wq(512) ; Wkv k(512) ; Wkv v(512)]; Wobf[256][512]
__global__ __launch_bounds__(256) void k_convert_w(
    const float* __restrict__ Wq, const float* __restrict__ Wkv,
    const float* __restrict__ Wo, u16* __restrict__ Wcat, u16* __restrict__ Wobf) {
  const int i = blockIdx.x * 256 + threadIdx.x;
  if (i < 131072) {
    Wcat[i] = f2bf(Wq[i]);
  } else if (i < 393216) {
    Wcat[i] = f2bf(Wkv[i - 131072]);
  } else {
    Wobf[i - 393216] = f2bf(Wo[i - 393216]);
  }
}

// ------------------------------------------------- x (4,256,128,128) -> xbT[p][c]
// v2 (round-14 proven): 1024 blocks; thread = (ch-group, pixel-sub).
__global__ __launch_bounds__(256) void k_convert_x(
    const float* __restrict__ x, u16* __restrict__ xbT) {
  const int psub = threadIdx.x & 63, cg = threadIdx.x >> 6;
  const int p = blockIdx.x * 64 + psub;   // 65536 pixels
  const int b = p >> 14, hw = p & 16383;
  const float* src = x + ((size_t)b << 22) + ((size_t)(cg * 64) << 14) + hw;
  u16* dst = xbT + ((size_t)p << 8) + cg * 64;
#pragma unroll
  for (int c0 = 0; c0 < 64; c0 += 8) {
    u16x8 v;
#pragma unroll
    for (int j = 0; j < 8; ++j)
      v[j] = f2bf(src[(size_t)(c0 + j) << 14]);
    *(u16x8*)(dst + c0) = v;
  }
}

// ---------------------------------------------------------------- GEMM template
// R15-proven: BK=64 dbuf, counted-vmcnt, XOR swizzle; MODE0 q/k epilogue via
// per-wave 2KB LDS transpose -> full-line 16B/lane stores.
// MODE 0: A=Wcat(1536x256), B=xbT[pixel][256] -> q/k [wh][tok][d], v [wh][d][tok]
// MODE 1: A=Wobf(256x512),  B=attnout [wh][token][d] chunks -> fp32 NCHW + bias
template <int KTOT, int MODE>
__global__ __launch_bounds__(512) void k_gemm(
    const u16* __restrict__ A, const u16* __restrict__ B,
    u16* __restrict__ qws, u16* __restrict__ kws, u16* __restrict__ vws,
    float* __restrict__ dout, const float* __restrict__ bo) {
  __shared__ __align__(16) char As[2][16384];  // [buf][128 rows][128B swz]
  __shared__ __align__(16) char Bs[2][16384];
  __shared__ __align__(16) u16 Ob[8][1024];    // per-wave 2KB transpose buffer
  const int tid = threadIdx.x;
  const int lane = tid & 63, wid = tid >> 6;
  const int wr = wid & 1, wc = wid >> 1;       // 2x4 wave grid
  const int l15 = lane & 15, lg = lane >> 4;
  const int MT = (MODE == 0) ? 12 : 2;
  // chunked XCD swizzle (bijective: nwg % 8 == 0)
  const int nwgPerXcd = (MODE == 0) ? 768 : 128;
  const int bid = (blockIdx.x & 7) * nwgPerXcd + (blockIdx.x >> 3);
  const int mt = bid % MT, nt = bid / MT;
  const int m0 = mt * 128, n0 = nt * 128;
  constexpr int NT = KTOT / 64;

  auto stage = [&](int buf, int k0) {
#pragma unroll
    for (int c = 0; c < 2; ++c) {
      const int u = c * 512 + tid;           // 16B-unit in 16KB tile
      const int row = u >> 3;                // tile row (128B)
      const int sb = ((u & 7) * 16) ^ ((row & 7) << 4);  // inv-swizzled byte
      gload16((const char*)A + ((size_t)(m0 + row) * KTOT + k0) * 2 + sb,
              As[buf] + u * 16);
      if constexpr (MODE == 0) {
        gload16((const char*)B + ((size_t)(n0 + row) * KTOT + k0) * 2 + sb,
                Bs[buf] + u * 16);
      } else {
        // remap pixel,channel -> [whb + head*64 windows][token][d]
        const int col = n0 + row;
        const int b = col >> 14, hw = col & 16383;
        const int h = hw >> 7, w = hw & 127;
        const int token = ((h & 15) << 4) | (w & 15);
        const int whb = (b << 9) + ((h >> 4) << 3) + (w >> 4);
        const int cch = k0 + (sb >> 1);      // channel (8-aligned)
        gload16(B + ((size_t)whb << 14) + ((size_t)(cch >> 6) << 20) +
                    token * 64 + (cch & 63),
                Bs[buf] + u * 16);
      }
    }
  };

  f32x4 acc[4][2] = {};

  stage(0, 0);
  int cur = 0;
  for (int t = 0; t < NT; ++t) {
    if (t + 1 < NT) {
      stage(cur ^ 1, (t + 1) * 64);
      asm volatile("s_waitcnt vmcnt(4)" ::: "memory");  // cur's 4 loads landed
    } else {
      asm volatile("s_waitcnt vmcnt(0)" ::: "memory");
    }
    __builtin_amdgcn_s_barrier();
    const char* Ab = As[cur];
    const char* Bb = Bs[cur];
#pragma unroll
    for (int kk = 0; kk < 2; ++kk) {
      bf16x8 af[4], bfr[2];
#pragma unroll
      for (int t4 = 0; t4 < 4; ++t4) {
        const int ra = wr * 64 + t4 * 16 + l15;
        af[t4] = *(const bf16x8*)(Ab + ra * 128 + ((kk * 64 + lg * 16) ^ ((ra & 7) << 4)));
      }
#pragma unroll
      for (int t2 = 0; t2 < 2; ++t2) {
        const int rb = wc * 32 + t2 * 16 + l15;
        bfr[t2] = *(const bf16x8*)(Bb + rb * 128 + ((kk * 64 + lg * 16) ^ ((rb & 7) << 4)));
      }
      __builtin_amdgcn_s_setprio(1);
#pragma unroll
      for (int i = 0; i < 4; ++i)
#pragma unroll
        for (int jj = 0; jj < 2; ++jj)
          acc[i][jj] = __builtin_amdgcn_mfma_f32_16x16x32_bf16(af[i], bfr[jj], acc[i][jj], 0, 0, 0);
      __builtin_amdgcn_s_setprio(0);
    }
    __builtin_amdgcn_s_barrier();
    cur ^= 1;
  }

  if (MODE == 0) {
    // q/k: idx = wh*16384 + token*64 + d ; v: idx = wh*16384 + d*256 + token
    u16* dst = (m0 < 512) ? qws : (m0 < 1024) ? kws : vws;
    const bool isv = (m0 >= 1024);
    if (!isv) {
      // q/k via per-wave LDS transpose -> 16B/lane full-line stores
      char* myOb = (char*)Ob[wid];
      const int t = lane >> 2, seg = lane & 3;
      const int head = ((m0 + wr * 64) & 511) >> 6;  // wave-uniform
#pragma unroll
      for (int ct = 0; ct < 2; ++ct) {
        const int col0 = n0 + wc * 32 + ct * 16;  // 16-aligned pixel base
        const int b0 = col0 >> 14, hw0 = col0 & 16383;
        const int h0 = hw0 >> 7, w0 = hw0 & 127;
        const int tok0 = (h0 & 15) << 4;          // 16-aligned token base
        const int whb = (b0 << 9) + ((h0 >> 4) << 3) + (w0 >> 4);
        u16* dstw = dst + ((size_t)(whb << 14) + (head << 20));
#pragma unroll
        for (int rt = 0; rt < 4; ++rt) {
          u32x2 pk2;
          pk2[0] = cvtpk(acc[rt][ct][0], acc[rt][ct][1]);
          pk2[1] = cvtpk(acc[rt][ct][2], acc[rt][ct][3]);
          *(u32x2*)(myOb + ((l15 * 128 + rt * 32 + lg * 8) ^ ((l15 & 7) << 4))) = pk2;
        }
        asm volatile("s_waitcnt lgkmcnt(0)" ::: "memory");
#pragma unroll
        for (int j = 0; j < 2; ++j) {
          u16x8 v = *(const u16x8*)(myOb + ((t * 128 + j * 64 + seg * 16) ^ ((t & 7) << 4)));
          *(u16x8*)(dstw + (tok0 + t) * 64 + j * 32 + seg * 8) = v;
        }
        asm volatile("s_waitcnt lgkmcnt(0)" ::: "memory");  // drain before reuse
      }
    } else {
#pragma unroll
      for (int ct = 0; ct < 2; ++ct) {
        const int col = n0 + wc * 32 + ct * 16 + l15;  // pixel
        const int b = col >> 14, hw = col & 16383;
        const int h = hw >> 7, w = hw & 127;
        const int token = ((h & 15) << 4) | (w & 15);
        const int npart = (((b << 9) + ((h >> 4) << 3) + (w >> 4)) << 14) + token;
#pragma unroll
        for (int rt = 0; rt < 4; ++rt)
#pragma unroll
          for (int r = 0; r < 4; ++r) {
            const int mm = (m0 + wr * 64 + rt * 16 + lg * 4 + r) & 511;
            const int head = mm >> 6, d = mm & 63;
            dst[(size_t)(npart + (head << 20) + (d << 8))] = f2bf(acc[rt][ct][r]);
          }
      }
    }
  } else {
#pragma unroll
    for (int rt = 0; rt < 4; ++rt)
#pragma unroll
      for (int r = 0; r < 4; ++r) {
        const int o = m0 + wr * 64 + rt * 16 + lg * 4 + r;
        const float bias = bo[o];
#pragma unroll
        for (int ct = 0; ct < 2; ++ct) {
          const int col = n0 + wc * 32 + ct * 16 + l15;  // pixel
          const int b = col >> 14, hw = col & 16383;
          dout[(((size_t)(b << 8) + o) << 14) + hw] = acc[rt][ct][r] + bias;
        }
      }
  }
}

// ---------------------------------------------------------------- attention
// v3: R15's proven 8-wave body (512 thr, 2 chunks/wave, 60 VGPR) with LDS
// halved: only K staged (32KB, XOR-swizzled); V fragments read DIRECTLY from
// global [wh][d][tok] (clean 16B/lane; 32KB/block working set -> L1/L2 hits
// after first touch). 32KB LDS -> 4 blocks/CU x 8 waves = 8 waves/SIMD (was 4).
// R16 lesson applied: register budget unchanged (launch_bounds(512,4)).
__global__ __launch_bounds__(512, 4) void k_attn(
    const u16* __restrict__ qws, const u16* __restrict__ kws,
    const u16* __restrict__ vws, u16* __restrict__ aout) {
  __shared__ __align__(16) u16 Ks[16384];   // 32KB swizzled [256][64]
  const int tid = threadIdx.x, lane = tid & 63, wid = tid >> 6;
  const int l15 = lane & 15, lg = lane >> 4;
  const int wh = blockIdx.x;
  const u16* qb = qws + ((size_t)wh << 14);
  const char* kbc = (const char*)(kws + ((size_t)wh << 14));
  const char* vbc = (const char*)(vws + ((size_t)wh << 14));
  u16* ob = aout + ((size_t)wh << 14);

  // Q fragments for both chunks (hoisted)
  bf16x8 qf[2][2];
#pragma unroll
  for (int chunk = 0; chunk < 2; ++chunk)
#pragma unroll
    for (int kk = 0; kk < 2; ++kk)
      qf[chunk][kk] = *(const bf16x8*)(qb + (wid * 32 + chunk * 16 + l15) * 64 +
                                       kk * 32 + lg * 8);

  // stage K only: linear LDS dest, inverse-swizzled global source
#pragma unroll
  for (int pass = 0; pass < 4; ++pass) {
    const int o = pass * 8192 + tid * 16;
    const int row = o >> 7, c = o & 127;  // K: 128B rows
    gload16(kbc + row * 128 + (c ^ ((row & 7) << 4)), (char*)Ks + o);
  }
  __syncthreads();

  const int idxA = ((lg & 1) << 5) + l15;  // src lane for P-frag low half
  const int idxB = idxA + 16;              // src lane for P-frag high half
  const bool useY = (lg & 2) != 0;         // ct-parity select
  const float cexp = 0.125f * 1.44269504088896f;  // SCALE * log2(e)

  f32x4 o4[2][4] = {};   // [chunk][dt] persistent across halves
  f32x4 sum4[2] = {};    // per-chunk partial softmax denominator

#pragma unroll
  for (int h = 0; h < 2; ++h) {
#pragma unroll
    for (int chunk = 0; chunk < 2; ++chunk) {
      // s[ct][r] = S[k = h*128 + ct*16 + lg*4 + r][q = l15]
      f32x4 s[8] = {};
      __builtin_amdgcn_s_setprio(1);
#pragma unroll
      for (int kk = 0; kk < 2; ++kk)
#pragma unroll
        for (int ct = 0; ct < 8; ++ct) {
          const int krow = h * 128 + ct * 16 + l15;
          bf16x8 kf = *(const bf16x8*)((const char*)Ks + krow * 128 +
                                       ((kk * 64 + lg * 16) ^ ((krow & 7) << 4)));
          s[ct] = __builtin_amdgcn_mfma_f32_16x16x32_bf16(kf, qf[chunk][kk], s[ct], 0, 0, 0);
        }
      __builtin_amdgcn_s_setprio(0);

      // p = exp2(s * cexp)  (no max-sub); vector tree-sum into sum4
#pragma unroll
      for (int ct = 0; ct < 8; ++ct) {
#pragma unroll
        for (int r = 0; r < 4; ++r) s[ct][r] = exp2f(s[ct][r] * cexp);
        sum4[chunk] += s[ct];
      }

      // pack P to bf16 pairs
      int pkLo[8], pkHi[8];
#pragma unroll
      for (int ct = 0; ct < 8; ++ct) {
        pkLo[ct] = (int)cvtpk(s[ct][0], s[ct][1]);
        pkHi[ct] = (int)cvtpk(s[ct][2], s[ct][3]);
      }

      // PV: O^T[d][q] += V^T-frag (A, from GLOBAL) x P-frag (B, via shfl)
#pragma unroll
      for (int kt = 0; kt < 4; ++kt) {
        const int ev = 2 * kt, od = 2 * kt + 1;
        int xa0 = __shfl(pkLo[ev], idxA), xa1 = __shfl(pkHi[ev], idxA);
        int xb0 = __shfl(pkLo[ev], idxB), xb1 = __shfl(pkHi[ev], idxB);
        int ya0 = __shfl(pkLo[od], idxA), ya1 = __shfl(pkHi[od], idxA);
        int yb0 = __shfl(pkLo[od], idxB), yb1 = __shfl(pkHi[od], idxB);
        u32x4 w;
        w[0] = (uint32_t)(useY ? ya0 : xa0);
        w[1] = (uint32_t)(useY ? ya1 : xa1);
        w[2] = (uint32_t)(useY ? yb0 : xb0);
        w[3] = (uint32_t)(useY ? yb1 : xb1);
        bf16x8 pf = __builtin_bit_cast(bf16x8, w);
        __builtin_amdgcn_s_setprio(1);
#pragma unroll
        for (int dt = 0; dt < 4; ++dt) {
          const int vrow = dt * 16 + l15;
          bf16x8 vf = *(const bf16x8*)(vbc + vrow * 512 +
                                       (h * 256 + kt * 64 + lg * 16));
          o4[chunk][dt] = __builtin_amdgcn_mfma_f32_16x16x32_bf16(vf, pf, o4[chunk][dt], 0, 0, 0);
        }
        __builtin_amdgcn_s_setprio(0);
      }
    }
  }

  // finalize: normalize and store O directly (lane q=l15 -> token row;
  // d = dt*16 + lg*4 + r). 8B/lane, 4 lg-lanes contiguous -> full 32B sectors.
#pragma unroll
  for (int chunk = 0; chunk < 2; ++chunk) {
    const int tok = wid * 32 + chunk * 16 + l15;
    float hs = (sum4[chunk][0] + sum4[chunk][1]) + (sum4[chunk][2] + sum4[chunk][3]);
    hs += __shfl_xor(hs, 16);
    hs += __shfl_xor(hs, 32);
    const float pinv = 1.0f / hs;
#pragma unroll
    for (int dt = 0; dt < 4; ++dt) {
      u32x2 pk;
      pk[0] = cvtpk(o4[chunk][dt][0] * pinv, o4[chunk][dt][1] * pinv);
      pk[1] = cvtpk(o4[chunk][dt][2] * pinv, o4[chunk][dt][3] * pinv);
      *(u32x2*)(ob + tok * 64 + dt * 16 + lg * 4) = pk;
    }
  }
}

extern "C" void kernel_launch(void* const* d_in, const int* in_sizes, int n_in,
                              void* d_out, int out_size, void* d_ws, size_t ws_size,
                              hipStream_t stream) {
  const float* x   = (const float*)d_in[0];
  const float* Wq  = (const float*)d_in[1];
  const float* Wkv = (const float*)d_in[2];
  const float* Wo  = (const float*)d_in[3];
  const float* bo  = (const float*)d_in[4];
  float* out = (float*)d_out;

  // workspace layout (161 MiB), same as rounds 9/12/14/15:
  //   [0, 32MiB)         xbT
  //   [32MiB, +768KiB)   Wcat
  //   [.., +256KiB)      Wobf
  //   [34603008, +64MiB) kws  (k_attn overwrites in-place with attnout;
  //                           K is LDS-resident after the staging barrier)
  //   [101711872,+64MiB) vws  (still read by k_attn PV: NOT aliased w/ aout)
  // q lives in d_out (64 MiB bf16), dead before final GEMM writes fp32 there.
  char* ws = (char*)d_ws;
  u16* xbT  = (u16*)ws;
  u16* Wcat = (u16*)(ws + 33554432);
  u16* Wobf = (u16*)(ws + 34340864);
  u16* kws  = (u16*)(ws + 34603008);
  u16* vws  = (u16*)(ws + 101711872);
  u16* qws  = (u16*)d_out;

  k_convert_w<<<2048, 256, 0, stream>>>(Wq, Wkv, Wo, Wcat, Wobf);
  k_convert_x<<<1024, 256, 0, stream>>>(x, xbT);
  k_gemm<256, 0><<<6144, 512, 0, stream>>>(Wcat, xbT, qws, kws, vws, nullptr, nullptr);
  k_attn<<<2048, 512, 0, stream>>>(qws, kws, vws, kws);
  k_gemm<512, 1><<<1024, 512, 0, stream>>>(Wobf, kws, nullptr, nullptr, nullptr, out, bo);
}

// Round 18
// 217.697 us; speedup vs baseline: 1.3804x; 1.3804x over previous
//
#include <hip/hip_runtime.h>
#include <stdint.h>

typedef unsigned short u16;
typedef short bf16x8 __attribute__((ext_vector_type(8)));
typedef float f32x4 __attribute__((ext_vector_type(4)));
typedef u16 u16x8 __attribute__((ext_vector_type(8)));
typedef u16 u16x4 __attribute__((ext_vector_type(4)));
typedef uint32_t u32x4 __attribute__((ext_vector_type(4)));
typedef uint32_t u32x2 __attribute__((ext_vector_type(2)));

typedef const __attribute__((address_space(1))) void gvoid_t;
typedef __attribute__((address_space(3))) void lvoid_t;

__device__ __forceinline__ u16 f2bf(float f) {
  uint32_t u = __float_as_uint(f);
  return (u16)((u + 0x7fffu + ((u >> 16) & 1u)) >> 16);
}

__device__ __forceinline__ uint32_t cvtpk(float a, float b) {
  uint32_t r;
  asm("v_cvt_pk_bf16_f32 %0, %1, %2" : "=v"(r) : "v"(a), "v"(b));
  return r;  // lo16 = bf16(a), hi16 = bf16(b)
}

__device__ __forceinline__ void gload16(const void* g, void* l) {
  __builtin_amdgcn_global_load_lds((gvoid_t*)g, (lvoid_t*)l, 16, 0, 0);
}

// ---------------------------------------------------------------- weights cast
// Wcat[1536][256] = [Wq(512) ; Wkv k(512) ; Wkv v(512)]; Wobf[256][512]
__global__ __launch_bounds__(256) void k_convert_w(
    const float* __restrict__ Wq, const float* __restrict__ Wkv,
    const float* __restrict__ Wo, u16* __restrict__ Wcat, u16* __restrict__ Wobf) {
  const int i = blockIdx.x * 256 + threadIdx.x;
  if (i < 131072) {
    Wcat[i] = f2bf(Wq[i]);
  } else if (i < 393216) {
    Wcat[i] = f2bf(Wkv[i - 131072]);
  } else {
    Wobf[i - 393216] = f2bf(Wo[i - 393216]);
  }
}

// ------------------------------------------------- x (4,256,128,128) -> xbT[p][c]
// v2 (round-14 proven): 1024 blocks; thread = (ch-group, pixel-sub).
__global__ __launch_bounds__(256) void k_convert_x(
    const float* __restrict__ x, u16* __restrict__ xbT) {
  const int psub = threadIdx.x & 63, cg = threadIdx.x >> 6;
  const int p = blockIdx.x * 64 + psub;   // 65536 pixels
  const int b = p >> 14, hw = p & 16383;
  const float* src = x + ((size_t)b << 22) + ((size_t)(cg * 64) << 14) + hw;
  u16* dst = xbT + ((size_t)p << 8) + cg * 64;
#pragma unroll
  for (int c0 = 0; c0 < 64; c0 += 8) {
    u16x8 v;
#pragma unroll
    for (int j = 0; j < 8; ++j)
      v[j] = f2bf(src[(size_t)(c0 + j) << 14]);
    *(u16x8*)(dst + c0) = v;
  }
}

// ---------------------------------------------------------------- GEMM template
// R15-proven: BK=64 dbuf, counted-vmcnt, XOR swizzle; MODE0 q/k epilogue via
// per-wave 2KB LDS transpose -> full-line 16B/lane stores.
// MODE 0: A=Wcat(1536x256), B=xbT[pixel][256] -> q/k [wh][tok][d], v [wh][d][tok]
// MODE 1: A=Wobf(256x512),  B=attnout [wh][token][d] chunks -> fp32 NCHW + bias
template <int KTOT, int MODE>
__global__ __launch_bounds__(512) void k_gemm(
    const u16* __restrict__ A, const u16* __restrict__ B,
    u16* __restrict__ qws, u16* __restrict__ kws, u16* __restrict__ vws,
    float* __restrict__ dout, const float* __restrict__ bo) {
  __shared__ __align__(16) char As[2][16384];  // [buf][128 rows][128B swz]
  __shared__ __align__(16) char Bs[2][16384];
  __shared__ __align__(16) u16 Ob[8][1024];    // per-wave 2KB transpose buffer
  const int tid = threadIdx.x;
  const int lane = tid & 63, wid = tid >> 6;
  const int wr = wid & 1, wc = wid >> 1;       // 2x4 wave grid
  const int l15 = lane & 15, lg = lane >> 4;
  const int MT = (MODE == 0) ? 12 : 2;
  // chunked XCD swizzle (bijective: nwg % 8 == 0)
  const int nwgPerXcd = (MODE == 0) ? 768 : 128;
  const int bid = (blockIdx.x & 7) * nwgPerXcd + (blockIdx.x >> 3);
  const int mt = bid % MT, nt = bid / MT;
  const int m0 = mt * 128, n0 = nt * 128;
  constexpr int NT = KTOT / 64;

  auto stage = [&](int buf, int k0) {
#pragma unroll
    for (int c = 0; c < 2; ++c) {
      const int u = c * 512 + tid;           // 16B-unit in 16KB tile
      const int row = u >> 3;                // tile row (128B)
      const int sb = ((u & 7) * 16) ^ ((row & 7) << 4);  // inv-swizzled byte
      gload16((const char*)A + ((size_t)(m0 + row) * KTOT + k0) * 2 + sb,
              As[buf] + u * 16);
      if constexpr (MODE == 0) {
        gload16((const char*)B + ((size_t)(n0 + row) * KTOT + k0) * 2 + sb,
                Bs[buf] + u * 16);
      } else {
        // remap pixel,channel -> [whb + head*64 windows][token][d]
        const int col = n0 + row;
        const int b = col >> 14, hw = col & 16383;
        const int h = hw >> 7, w = hw & 127;
        const int token = ((h & 15) << 4) | (w & 15);
        const int whb = (b << 9) + ((h >> 4) << 3) + (w >> 4);
        const int cch = k0 + (sb >> 1);      // channel (8-aligned)
        gload16(B + ((size_t)whb << 14) + ((size_t)(cch >> 6) << 20) +
                    token * 64 + (cch & 63),
                Bs[buf] + u * 16);
      }
    }
  };

  f32x4 acc[4][2] = {};

  stage(0, 0);
  int cur = 0;
  for (int t = 0; t < NT; ++t) {
    if (t + 1 < NT) {
      stage(cur ^ 1, (t + 1) * 64);
      asm volatile("s_waitcnt vmcnt(4)" ::: "memory");  // cur's 4 loads landed
    } else {
      asm volatile("s_waitcnt vmcnt(0)" ::: "memory");
    }
    __builtin_amdgcn_s_barrier();
    const char* Ab = As[cur];
    const char* Bb = Bs[cur];
#pragma unroll
    for (int kk = 0; kk < 2; ++kk) {
      bf16x8 af[4], bfr[2];
#pragma unroll
      for (int t4 = 0; t4 < 4; ++t4) {
        const int ra = wr * 64 + t4 * 16 + l15;
        af[t4] = *(const bf16x8*)(Ab + ra * 128 + ((kk * 64 + lg * 16) ^ ((ra & 7) << 4)));
      }
#pragma unroll
      for (int t2 = 0; t2 < 2; ++t2) {
        const int rb = wc * 32 + t2 * 16 + l15;
        bfr[t2] = *(const bf16x8*)(Bb + rb * 128 + ((kk * 64 + lg * 16) ^ ((rb & 7) << 4)));
      }
      __builtin_amdgcn_s_setprio(1);
#pragma unroll
      for (int i = 0; i < 4; ++i)
#pragma unroll
        for (int jj = 0; jj < 2; ++jj)
          acc[i][jj] = __builtin_amdgcn_mfma_f32_16x16x32_bf16(af[i], bfr[jj], acc[i][jj], 0, 0, 0);
      __builtin_amdgcn_s_setprio(0);
    }
    __builtin_amdgcn_s_barrier();
    cur ^= 1;
  }

  if (MODE == 0) {
    // q/k: idx = wh*16384 + token*64 + d ; v: idx = wh*16384 + d*256 + token
    u16* dst = (m0 < 512) ? qws : (m0 < 1024) ? kws : vws;
    const bool isv = (m0 >= 1024);
    if (!isv) {
      // q/k via per-wave LDS transpose -> 16B/lane full-line stores
      char* myOb = (char*)Ob[wid];
      const int t = lane >> 2, seg = lane & 3;
      const int head = ((m0 + wr * 64) & 511) >> 6;  // wave-uniform
#pragma unroll
      for (int ct = 0; ct < 2; ++ct) {
        const int col0 = n0 + wc * 32 + ct * 16;  // 16-aligned pixel base
        const int b0 = col0 >> 14, hw0 = col0 & 16383;
        const int h0 = hw0 >> 7, w0 = hw0 & 127;
        const int tok0 = (h0 & 15) << 4;          // 16-aligned token base
        const int whb = (b0 << 9) + ((h0 >> 4) << 3) + (w0 >> 4);
        u16* dstw = dst + ((size_t)(whb << 14) + (head << 20));
#pragma unroll
        for (int rt = 0; rt < 4; ++rt) {
          u32x2 pk2;
          pk2[0] = cvtpk(acc[rt][ct][0], acc[rt][ct][1]);
          pk2[1] = cvtpk(acc[rt][ct][2], acc[rt][ct][3]);
          *(u32x2*)(myOb + ((l15 * 128 + rt * 32 + lg * 8) ^ ((l15 & 7) << 4))) = pk2;
        }
        asm volatile("s_waitcnt lgkmcnt(0)" ::: "memory");
#pragma unroll
        for (int j = 0; j < 2; ++j) {
          u16x8 v = *(const u16x8*)(myOb + ((t * 128 + j * 64 + seg * 16) ^ ((t & 7) << 4)));
          *(u16x8*)(dstw + (tok0 + t) * 64 + j * 32 + seg * 8) = v;
        }
        asm volatile("s_waitcnt lgkmcnt(0)" ::: "memory");  // drain before reuse
      }
    } else {
#pragma unroll
      for (int ct = 0; ct < 2; ++ct) {
        const int col = n0 + wc * 32 + ct * 16 + l15;  // pixel
        const int b = col >> 14, hw = col & 16383;
        const int h = hw >> 7, w = hw & 127;
        const int token = ((h & 15) << 4) | (w & 15);
        const int npart = (((b << 9) + ((h >> 4) << 3) + (w >> 4)) << 14) + token;
#pragma unroll
        for (int rt = 0; rt < 4; ++rt)
#pragma unroll
          for (int r = 0; r < 4; ++r) {
            const int mm = (m0 + wr * 64 + rt * 16 + lg * 4 + r) & 511;
            const int head = mm >> 6, d = mm & 63;
            dst[(size_t)(npart + (head << 20) + (d << 8))] = f2bf(acc[rt][ct][r]);
          }
      }
    }
  } else {
#pragma unroll
    for (int rt = 0; rt < 4; ++rt)
#pragma unroll
      for (int r = 0; r < 4; ++r) {
        const int o = m0 + wr * 64 + rt * 16 + lg * 4 + r;
        const float bias = bo[o];
#pragma unroll
        for (int ct = 0; ct < 2; ++ct) {
          const int col = n0 + wc * 32 + ct * 16 + l15;  // pixel
          const int b = col >> 14, hw = col & 16383;
          dout[(((size_t)(b << 8) + o) << 14) + hw] = acc[rt][ct][r] + bias;
        }
      }
  }
}

// ---------------------------------------------------------------- attention
// v4: R15's proven 8-wave compute body (512 thr, 2 chunks/wave, ~60 VGPR),
// with K/V staged PER TOKEN-HALF inside the h-loop: K-half [128][64] 16KB +
// V^T-half [64][128] 16KB, XOR-swizzled, gload16 + __syncthreads() only
// (no counted vmcnt). Resident LDS 32KB -> 4 blocks/CU -> 8 waves/SIMD
// (R15 was 2 blocks / 4 waves). R16 lesson: register budget unchanged.
// R17 lesson: V must be LDS-staged (global-direct PV is latency-serialized).
__global__ __launch_bounds__(512, 4) void k_attn(
    const u16* __restrict__ qws, const u16* __restrict__ kws,
    const u16* __restrict__ vws, u16* __restrict__ aout) {
  __shared__ __align__(16) u16 Ks[8192];   // 16KB swizzled [128 tok][64 d]
  __shared__ __align__(16) u16 Vs[8192];   // 16KB swizzled [64 d][128 tok]
  const int tid = threadIdx.x, lane = tid & 63, wid = tid >> 6;
  const int l15 = lane & 15, lg = lane >> 4;
  const int wh = blockIdx.x;
  const u16* qb = qws + ((size_t)wh << 14);
  const char* kbc = (const char*)(kws + ((size_t)wh << 14));
  const char* vbc = (const char*)(vws + ((size_t)wh << 14));
  u16* ob = aout + ((size_t)wh << 14);

  // Q fragments for both chunks (hoisted)
  bf16x8 qf[2][2];
#pragma unroll
  for (int chunk = 0; chunk < 2; ++chunk)
#pragma unroll
    for (int kk = 0; kk < 2; ++kk)
      qf[chunk][kk] = *(const bf16x8*)(qb + (wid * 32 + chunk * 16 + l15) * 64 +
                                       kk * 32 + lg * 8);

  const int idxA = ((lg & 1) << 5) + l15;  // src lane for P-frag low half
  const int idxB = idxA + 16;              // src lane for P-frag high half
  const bool useY = (lg & 2) != 0;         // ct-parity select
  const float cexp = 0.125f * 1.44269504088896f;  // SCALE * log2(e)

  f32x4 o4[2][4] = {};   // [chunk][dt] persistent across halves
  f32x4 sum4[2] = {};    // per-chunk partial softmax denominator

#pragma unroll
  for (int h = 0; h < 2; ++h) {
    // stage this token-half: K [128][64] + V^T [64][128], inverse-swizzled src
#pragma unroll
    for (int pass = 0; pass < 2; ++pass) {
      const int o = pass * 8192 + tid * 16;
      {
        const int row = o >> 7, c = o & 127;  // K half: 128B rows
        gload16(kbc + (h * 128 + row) * 128 + (c ^ ((row & 7) << 4)),
                (char*)Ks + o);
      }
      {
        const int row = o >> 8, c = o & 255;  // V^T half: 256B rows (of 512B)
        gload16(vbc + row * 512 + h * 256 + (c ^ ((row & 7) << 4)),
                (char*)Vs + o);
      }
    }
    __syncthreads();

#pragma unroll
    for (int chunk = 0; chunk < 2; ++chunk) {
      // s[ct][r] = S[k = h*128 + ct*16 + lg*4 + r][q = l15]
      f32x4 s[8] = {};
      __builtin_amdgcn_s_setprio(1);
#pragma unroll
      for (int kk = 0; kk < 2; ++kk)
#pragma unroll
        for (int ct = 0; ct < 8; ++ct) {
          const int krow = ct * 16 + l15;  // local 0..127
          bf16x8 kf = *(const bf16x8*)((const char*)Ks + krow * 128 +
                                       ((kk * 64 + lg * 16) ^ ((krow & 7) << 4)));
          s[ct] = __builtin_amdgcn_mfma_f32_16x16x32_bf16(kf, qf[chunk][kk], s[ct], 0, 0, 0);
        }
      __builtin_amdgcn_s_setprio(0);

      // p = exp2(s * cexp)  (no max-sub); vector tree-sum into sum4
#pragma unroll
      for (int ct = 0; ct < 8; ++ct) {
#pragma unroll
        for (int r = 0; r < 4; ++r) s[ct][r] = exp2f(s[ct][r] * cexp);
        sum4[chunk] += s[ct];
      }

      // pack P to bf16 pairs
      int pkLo[8], pkHi[8];
#pragma unroll
      for (int ct = 0; ct < 8; ++ct) {
        pkLo[ct] = (int)cvtpk(s[ct][0], s[ct][1]);
        pkHi[ct] = (int)cvtpk(s[ct][2], s[ct][3]);
      }

      // PV: O^T[d][q] += V^T-frag (A) x P-frag (B); P-frag via shfl:
      // lane(l15,lg) needs P[k_local=kt*32+lg*8+e][q=l15]: ct'=2kt+(lg>>1),
      // e0..3 from lane 32*(lg&1)+l15, e4..7 from +16.
#pragma unroll
      for (int kt = 0; kt < 4; ++kt) {
        const int ev = 2 * kt, od = 2 * kt + 1;
        int xa0 = __shfl(pkLo[ev], idxA), xa1 = __shfl(pkHi[ev], idxA);
        int xb0 = __shfl(pkLo[ev], idxB), xb1 = __shfl(pkHi[ev], idxB);
        int ya0 = __shfl(pkLo[od], idxA), ya1 = __shfl(pkHi[od], idxA);
        int yb0 = __shfl(pkLo[od], idxB), yb1 = __shfl(pkHi[od], idxB);
        u32x4 w;
        w[0] = (uint32_t)(useY ? ya0 : xa0);
        w[1] = (uint32_t)(useY ? ya1 : xa1);
        w[2] = (uint32_t)(useY ? yb0 : xb0);
        w[3] = (uint32_t)(useY ? yb1 : xb1);
        bf16x8 pf = __builtin_bit_cast(bf16x8, w);
        __builtin_amdgcn_s_setprio(1);
#pragma unroll
        for (int dt = 0; dt < 4; ++dt) {
          const int vrow = dt * 16 + l15;
          bf16x8 vf = *(const bf16x8*)((const char*)Vs + vrow * 256 +
                                       ((kt * 64 + lg * 16) ^ ((vrow & 7) << 4)));
          o4[chunk][dt] = __builtin_amdgcn_mfma_f32_16x16x32_bf16(vf, pf, o4[chunk][dt], 0, 0, 0);
        }
        __builtin_amdgcn_s_setprio(0);
      }
    }
    __syncthreads();  // all waves done with this half before re-staging
  }

  // finalize: normalize and store O directly (lane q=l15 -> token row;
  // d = dt*16 + lg*4 + r). 8B/lane, 4 lg-lanes contiguous -> full 32B sectors.
#pragma unroll
  for (int chunk = 0; chunk < 2; ++chunk) {
    const int tok = wid * 32 + chunk * 16 + l15;
    float hs = (sum4[chunk][0] + sum4[chunk][1]) + (sum4[chunk][2] + sum4[chunk][3]);
    hs += __shfl_xor(hs, 16);
    hs += __shfl_xor(hs, 32);
    const float pinv = 1.0f / hs;
#pragma unroll
    for (int dt = 0; dt < 4; ++dt) {
      u32x2 pk;
      pk[0] = cvtpk(o4[chunk][dt][0] * pinv, o4[chunk][dt][1] * pinv);
      pk[1] = cvtpk(o4[chunk][dt][2] * pinv, o4[chunk][dt][3] * pinv);
      *(u32x2*)(ob + tok * 64 + dt * 16 + lg * 4) = pk;
    }
  }
}

extern "C" void kernel_launch(void* const* d_in, const int* in_sizes, int n_in,
                              void* d_out, int out_size, void* d_ws, size_t ws_size,
                              hipStream_t stream) {
  const float* x   = (const float*)d_in[0];
  const float* Wq  = (const float*)d_in[1];
  const float* Wkv = (const float*)d_in[2];
  const float* Wo  = (const float*)d_in[3];
  const float* bo  = (const float*)d_in[4];
  float* out = (float*)d_out;

  // workspace layout (161 MiB), same as rounds 9/12/14/15:
  //   [0, 32MiB)         xbT
  //   [32MiB, +768KiB)   Wcat
  //   [.., +256KiB)      Wobf
  //   [34603008, +64MiB) kws  (k_attn overwrites in-place with attnout; all
  //                           K-half global reads precede O stores in-block)
  //   [101711872,+64MiB) vws
  // q lives in d_out (64 MiB bf16), dead before final GEMM writes fp32 there.
  char* ws = (char*)d_ws;
  u16* xbT  = (u16*)ws;
  u16* Wcat = (u16*)(ws + 33554432);
  u16* Wobf = (u16*)(ws + 34340864);
  u16* kws  = (u16*)(ws + 34603008);
  u16* vws  = (u16*)(ws + 101711872);
  u16* qws  = (u16*)d_out;

  k_convert_w<<<2048, 256, 0, stream>>>(Wq, Wkv, Wo, Wcat, Wobf);
  k_convert_x<<<1024, 256, 0, stream>>>(x, xbT);
  k_gemm<256, 0><<<6144, 512, 0, stream>>>(Wcat, xbT, qws, kws, vws, nullptr, nullptr);
  k_attn<<<2048, 512, 0, stream>>>(qws, kws, vws, kws);
  k_gemm<512, 1><<<1024, 512, 0, stream>>>(Wobf, kws, nullptr, nullptr, nullptr, out, bo);
}

// Round 19
// 208.778 us; speedup vs baseline: 1.4394x; 1.0427x over previous
//
#include <hip/hip_runtime.h>
#include <stdint.h>

typedef unsigned short u16;
typedef short bf16x8 __attribute__((ext_vector_type(8)));
typedef float f32x4 __attribute__((ext_vector_type(4)));
typedef u16 u16x8 __attribute__((ext_vector_type(8)));
typedef u16 u16x4 __attribute__((ext_vector_type(4)));
typedef uint32_t u32x4 __attribute__((ext_vector_type(4)));
typedef uint32_t u32x2 __attribute__((ext_vector_type(2)));

typedef const __attribute__((address_space(1))) void gvoid_t;
typedef __attribute__((address_space(3))) void lvoid_t;

__device__ __forceinline__ u16 f2bf(float f) {
  uint32_t u = __float_as_uint(f);
  return (u16)((u + 0x7fffu + ((u >> 16) & 1u)) >> 16);
}

__device__ __forceinline__ uint32_t cvtpk(float a, float b) {
  uint32_t r;
  asm("v_cvt_pk_bf16_f32 %0, %1, %2" : "=v"(r) : "v"(a), "v"(b));
  return r;  // lo16 = bf16(a), hi16 = bf16(b)
}

__device__ __forceinline__ void gload16(const void* g, void* l) {
  __builtin_amdgcn_global_load_lds((gvoid_t*)g, (lvoid_t*)l, 16, 0, 0);
}

// ---------------------------------------------------------------- weights cast
// Wcat[1536][256] = [Wq(512) ; Wkv k(512) ; Wkv v(512)]; Wobf[256][512]
__global__ __launch_bounds__(256) void k_convert_w(
    const float* __restrict__ Wq, const float* __restrict__ Wkv,
    const float* __restrict__ Wo, u16* __restrict__ Wcat, u16* __restrict__ Wobf) {
  const int i = blockIdx.x * 256 + threadIdx.x;
  if (i < 131072) {
    Wcat[i] = f2bf(Wq[i]);
  } else if (i < 393216) {
    Wcat[i] = f2bf(Wkv[i - 131072]);
  } else {
    Wobf[i - 393216] = f2bf(Wo[i - 393216]);
  }
}

// ------------------------------------------------- x (4,256,128,128) -> xbT[p][c]
// v2 (round-14 proven): 1024 blocks; thread = (ch-group, pixel-sub).
__global__ __launch_bounds__(256) void k_convert_x(
    const float* __restrict__ x, u16* __restrict__ xbT) {
  const int psub = threadIdx.x & 63, cg = threadIdx.x >> 6;
  const int p = blockIdx.x * 64 + psub;   // 65536 pixels
  const int b = p >> 14, hw = p & 16383;
  const float* src = x + ((size_t)b << 22) + ((size_t)(cg * 64) << 14) + hw;
  u16* dst = xbT + ((size_t)p << 8) + cg * 64;
#pragma unroll
  for (int c0 = 0; c0 < 64; c0 += 8) {
    u16x8 v;
#pragma unroll
    for (int j = 0; j < 8; ++j)
      v[j] = f2bf(src[(size_t)(c0 + j) << 14]);
    *(u16x8*)(dst + c0) = v;
  }
}

// ---------------------------------------------------------------- GEMM template
// R15-proven: BK=64 dbuf, counted-vmcnt, XOR swizzle; MODE0 q/k epilogue via
// per-wave 2KB LDS transpose -> full-line 16B/lane stores.
// MODE 0: A=Wcat(1536x256), B=xbT[pixel][256] -> q/k [wh][tok][d], v [wh][d][tok]
// MODE 1: A=Wobf(256x512),  B=attnout [wh][token][d] chunks -> fp32 NCHW + bias
template <int KTOT, int MODE>
__global__ __launch_bounds__(512) void k_gemm(
    const u16* __restrict__ A, const u16* __restrict__ B,
    u16* __restrict__ qws, u16* __restrict__ kws, u16* __restrict__ vws,
    float* __restrict__ dout, const float* __restrict__ bo) {
  __shared__ __align__(16) char As[2][16384];  // [buf][128 rows][128B swz]
  __shared__ __align__(16) char Bs[2][16384];
  __shared__ __align__(16) u16 Ob[8][1024];    // per-wave 2KB transpose buffer
  const int tid = threadIdx.x;
  const int lane = tid & 63, wid = tid >> 6;
  const int wr = wid & 1, wc = wid >> 1;       // 2x4 wave grid
  const int l15 = lane & 15, lg = lane >> 4;
  const int MT = (MODE == 0) ? 12 : 2;
  // chunked XCD swizzle (bijective: nwg % 8 == 0)
  const int nwgPerXcd = (MODE == 0) ? 768 : 128;
  const int bid = (blockIdx.x & 7) * nwgPerXcd + (blockIdx.x >> 3);
  const int mt = bid % MT, nt = bid / MT;
  const int m0 = mt * 128, n0 = nt * 128;
  constexpr int NT = KTOT / 64;

  auto stage = [&](int buf, int k0) {
#pragma unroll
    for (int c = 0; c < 2; ++c) {
      const int u = c * 512 + tid;           // 16B-unit in 16KB tile
      const int row = u >> 3;                // tile row (128B)
      const int sb = ((u & 7) * 16) ^ ((row & 7) << 4);  // inv-swizzled byte
      gload16((const char*)A + ((size_t)(m0 + row) * KTOT + k0) * 2 + sb,
              As[buf] + u * 16);
      if constexpr (MODE == 0) {
        gload16((const char*)B + ((size_t)(n0 + row) * KTOT + k0) * 2 + sb,
                Bs[buf] + u * 16);
      } else {
        // remap pixel,channel -> [whb + head*64 windows][token][d]
        const int col = n0 + row;
        const int b = col >> 14, hw = col & 16383;
        const int h = hw >> 7, w = hw & 127;
        const int token = ((h & 15) << 4) | (w & 15);
        const int whb = (b << 9) + ((h >> 4) << 3) + (w >> 4);
        const int cch = k0 + (sb >> 1);      // channel (8-aligned)
        gload16(B + ((size_t)whb << 14) + ((size_t)(cch >> 6) << 20) +
                    token * 64 + (cch & 63),
                Bs[buf] + u * 16);
      }
    }
  };

  f32x4 acc[4][2] = {};

  stage(0, 0);
  int cur = 0;
  for (int t = 0; t < NT; ++t) {
    if (t + 1 < NT) {
      stage(cur ^ 1, (t + 1) * 64);
      asm volatile("s_waitcnt vmcnt(4)" ::: "memory");  // cur's 4 loads landed
    } else {
      asm volatile("s_waitcnt vmcnt(0)" ::: "memory");
    }
    __builtin_amdgcn_s_barrier();
    const char* Ab = As[cur];
    const char* Bb = Bs[cur];
#pragma unroll
    for (int kk = 0; kk < 2; ++kk) {
      bf16x8 af[4], bfr[2];
#pragma unroll
      for (int t4 = 0; t4 < 4; ++t4) {
        const int ra = wr * 64 + t4 * 16 + l15;
        af[t4] = *(const bf16x8*)(Ab + ra * 128 + ((kk * 64 + lg * 16) ^ ((ra & 7) << 4)));
      }
#pragma unroll
      for (int t2 = 0; t2 < 2; ++t2) {
        const int rb = wc * 32 + t2 * 16 + l15;
        bfr[t2] = *(const bf16x8*)(Bb + rb * 128 + ((kk * 64 + lg * 16) ^ ((rb & 7) << 4)));
      }
      __builtin_amdgcn_s_setprio(1);
#pragma unroll
      for (int i = 0; i < 4; ++i)
#pragma unroll
        for (int jj = 0; jj < 2; ++jj)
          acc[i][jj] = __builtin_amdgcn_mfma_f32_16x16x32_bf16(af[i], bfr[jj], acc[i][jj], 0, 0, 0);
      __builtin_amdgcn_s_setprio(0);
    }
    __builtin_amdgcn_s_barrier();
    cur ^= 1;
  }

  if (MODE == 0) {
    // q/k: idx = wh*16384 + token*64 + d ; v: idx = wh*16384 + d*256 + token
    u16* dst = (m0 < 512) ? qws : (m0 < 1024) ? kws : vws;
    const bool isv = (m0 >= 1024);
    if (!isv) {
      // q/k via per-wave LDS transpose -> 16B/lane full-line stores
      char* myOb = (char*)Ob[wid];
      const int t = lane >> 2, seg = lane & 3;
      const int head = ((m0 + wr * 64) & 511) >> 6;  // wave-uniform
#pragma unroll
      for (int ct = 0; ct < 2; ++ct) {
        const int col0 = n0 + wc * 32 + ct * 16;  // 16-aligned pixel base
        const int b0 = col0 >> 14, hw0 = col0 & 16383;
        const int h0 = hw0 >> 7, w0 = hw0 & 127;
        const int tok0 = (h0 & 15) << 4;          // 16-aligned token base
        const int whb = (b0 << 9) + ((h0 >> 4) << 3) + (w0 >> 4);
        u16* dstw = dst + ((size_t)(whb << 14) + (head << 20));
#pragma unroll
        for (int rt = 0; rt < 4; ++rt) {
          u32x2 pk2;
          pk2[0] = cvtpk(acc[rt][ct][0], acc[rt][ct][1]);
          pk2[1] = cvtpk(acc[rt][ct][2], acc[rt][ct][3]);
          *(u32x2*)(myOb + ((l15 * 128 + rt * 32 + lg * 8) ^ ((l15 & 7) << 4))) = pk2;
        }
        asm volatile("s_waitcnt lgkmcnt(0)" ::: "memory");
#pragma unroll
        for (int j = 0; j < 2; ++j) {
          u16x8 v = *(const u16x8*)(myOb + ((t * 128 + j * 64 + seg * 16) ^ ((t & 7) << 4)));
          *(u16x8*)(dstw + (tok0 + t) * 64 + j * 32 + seg * 8) = v;
        }
        asm volatile("s_waitcnt lgkmcnt(0)" ::: "memory");  // drain before reuse
      }
    } else {
#pragma unroll
      for (int ct = 0; ct < 2; ++ct) {
        const int col = n0 + wc * 32 + ct * 16 + l15;  // pixel
        const int b = col >> 14, hw = col & 16383;
        const int h = hw >> 7, w = hw & 127;
        const int token = ((h & 15) << 4) | (w & 15);
        const int npart = (((b << 9) + ((h >> 4) << 3) + (w >> 4)) << 14) + token;
#pragma unroll
        for (int rt = 0; rt < 4; ++rt)
#pragma unroll
          for (int r = 0; r < 4; ++r) {
            const int mm = (m0 + wr * 64 + rt * 16 + lg * 4 + r) & 511;
            const int head = mm >> 6, d = mm & 63;
            dst[(size_t)(npart + (head << 20) + (d << 8))] = f2bf(acc[rt][ct][r]);
          }
      }
    }
  } else {
#pragma unroll
    for (int rt = 0; rt < 4; ++rt)
#pragma unroll
      for (int r = 0; r < 4; ++r) {
        const int o = m0 + wr * 64 + rt * 16 + lg * 4 + r;
        const float bias = bo[o];
#pragma unroll
        for (int ct = 0; ct < 2; ++ct) {
          const int col = n0 + wc * 32 + ct * 16 + l15;  // pixel
          const int b = col >> 14, hw = col & 16383;
          dout[(((size_t)(b << 8) + o) << 14) + hw] = acc[rt][ct][r] + bias;
        }
      }
  }
}

// ---------------------------------------------------------------- attention
// BYTE-EXACT R15 revert (best measured: 78.7 us). 8 waves (512 thr), wave owns
// 32 q-rows (2 chunks). Full K [256][64] + V^T [64][256] staged XOR-swizzled
// via ONE __syncthreads(). Swapped QK^T, no max-sub, register P via shfl,
// direct coalesced O stores. R16/R17/R18 lessons: do not starve registers, do
// not read V from global, do not barrier-split the staging.
__global__ __launch_bounds__(512, 4) void k_attn(
    const u16* __restrict__ qws, const u16* __restrict__ kws,
    const u16* __restrict__ vws, u16* __restrict__ aout) {
  __shared__ __align__(16) u16 Ks[16384];   // 32KB swizzled [256][64]
  __shared__ __align__(16) u16 Vs[16384];   // 32KB swizzled [64][256]
  const int tid = threadIdx.x, lane = tid & 63, wid = tid >> 6;
  const int l15 = lane & 15, lg = lane >> 4;
  const int wh = blockIdx.x;
  const u16* qb = qws + ((size_t)wh << 14);
  const char* kbc = (const char*)(kws + ((size_t)wh << 14));
  const char* vbc = (const char*)(vws + ((size_t)wh << 14));
  u16* ob = aout + ((size_t)wh << 14);

  // Q fragments for both chunks (hoisted)
  bf16x8 qf[2][2];
#pragma unroll
  for (int chunk = 0; chunk < 2; ++chunk)
#pragma unroll
    for (int kk = 0; kk < 2; ++kk)
      qf[chunk][kk] = *(const bf16x8*)(qb + (wid * 32 + chunk * 16 + l15) * 64 +
                                       kk * 32 + lg * 8);

  // stage K and V^T: linear LDS dest, inverse-swizzled global source
#pragma unroll
  for (int pass = 0; pass < 4; ++pass) {
    const int o = pass * 8192 + tid * 16;
    {
      const int row = o >> 7, c = o & 127;  // K: 128B rows
      gload16(kbc + row * 128 + (c ^ ((row & 7) << 4)), (char*)Ks + o);
    }
    {
      const int row = o >> 9, c = o & 511;  // V^T: 512B rows
      gload16(vbc + row * 512 + (c ^ ((row & 7) << 4)), (char*)Vs + o);
    }
  }
  __syncthreads();

  const int idxA = ((lg & 1) << 5) + l15;  // src lane for P-frag low half
  const int idxB = idxA + 16;              // src lane for P-frag high half
  const bool useY = (lg & 2) != 0;         // ct-parity select
  const float cexp = 0.125f * 1.44269504088896f;  // SCALE * log2(e)

  f32x4 o4[2][4] = {};   // [chunk][dt] persistent across halves
  f32x4 sum4[2] = {};    // per-chunk partial softmax denominator

#pragma unroll
  for (int h = 0; h < 2; ++h) {
#pragma unroll
    for (int chunk = 0; chunk < 2; ++chunk) {
      // s[ct][r] = S[k = h*128 + ct*16 + lg*4 + r][q = l15]
      f32x4 s[8] = {};
      __builtin_amdgcn_s_setprio(1);
#pragma unroll
      for (int kk = 0; kk < 2; ++kk)
#pragma unroll
        for (int ct = 0; ct < 8; ++ct) {
          const int krow = h * 128 + ct * 16 + l15;
          bf16x8 kf = *(const bf16x8*)((const char*)Ks + krow * 128 +
                                       ((kk * 64 + lg * 16) ^ ((krow & 7) << 4)));
          s[ct] = __builtin_amdgcn_mfma_f32_16x16x32_bf16(kf, qf[chunk][kk], s[ct], 0, 0, 0);
        }
      __builtin_amdgcn_s_setprio(0);

      // p = exp2(s * cexp)  (no max-sub); vector tree-sum into sum4
#pragma unroll
      for (int ct = 0; ct < 8; ++ct) {
#pragma unroll
        for (int r = 0; r < 4; ++r) s[ct][r] = exp2f(s[ct][r] * cexp);
        sum4[chunk] += s[ct];
      }

      // pack P to bf16 pairs
      int pkLo[8], pkHi[8];
#pragma unroll
      for (int ct = 0; ct < 8; ++ct) {
        pkLo[ct] = (int)cvtpk(s[ct][0], s[ct][1]);
        pkHi[ct] = (int)cvtpk(s[ct][2], s[ct][3]);
      }

      // PV: O^T[d][q] += V^T-frag (A) x P-frag (B); P-frag via shfl:
      // lane(l15,lg) needs P[k_local=kt*32+lg*8+e][q=l15]: ct'=2kt+(lg>>1),
      // e0..3 from lane 32*(lg&1)+l15, e4..7 from +16.
#pragma unroll
      for (int kt = 0; kt < 4; ++kt) {
        const int ev = 2 * kt, od = 2 * kt + 1;
        int xa0 = __shfl(pkLo[ev], idxA), xa1 = __shfl(pkHi[ev], idxA);
        int xb0 = __shfl(pkLo[ev], idxB), xb1 = __shfl(pkHi[ev], idxB);
        int ya0 = __shfl(pkLo[od], idxA), ya1 = __shfl(pkHi[od], idxA);
        int yb0 = __shfl(pkLo[od], idxB), yb1 = __shfl(pkHi[od], idxB);
        u32x4 w;
        w[0] = (uint32_t)(useY ? ya0 : xa0);
        w[1] = (uint32_t)(useY ? ya1 : xa1);
        w[2] = (uint32_t)(useY ? yb0 : xb0);
        w[3] = (uint32_t)(useY ? yb1 : xb1);
        bf16x8 pf = __builtin_bit_cast(bf16x8, w);
        __builtin_amdgcn_s_setprio(1);
#pragma unroll
        for (int dt = 0; dt < 4; ++dt) {
          const int vrow = dt * 16 + l15;
          bf16x8 vf = *(const bf16x8*)((const char*)Vs + vrow * 512 +
                                       ((h * 256 + kt * 64 + lg * 16) ^ ((vrow & 7) << 4)));
          o4[chunk][dt] = __builtin_amdgcn_mfma_f32_16x16x32_bf16(vf, pf, o4[chunk][dt], 0, 0, 0);
        }
        __builtin_amdgcn_s_setprio(0);
      }
    }
  }

  // finalize: normalize and store O directly (lane q=l15 -> token row;
  // d = dt*16 + lg*4 + r). 8B/lane, 4 lg-lanes contiguous -> full 32B sectors.
#pragma unroll
  for (int chunk = 0; chunk < 2; ++chunk) {
    const int tok = wid * 32 + chunk * 16 + l15;
    float hs = (sum4[chunk][0] + sum4[chunk][1]) + (sum4[chunk][2] + sum4[chunk][3]);
    hs += __shfl_xor(hs, 16);
    hs += __shfl_xor(hs, 32);
    const float pinv = 1.0f / hs;
#pragma unroll
    for (int dt = 0; dt < 4; ++dt) {
      u32x2 pk;
      pk[0] = cvtpk(o4[chunk][dt][0] * pinv, o4[chunk][dt][1] * pinv);
      pk[1] = cvtpk(o4[chunk][dt][2] * pinv, o4[chunk][dt][3] * pinv);
      *(u32x2*)(ob + tok * 64 + dt * 16 + lg * 4) = pk;
    }
  }
}

extern "C" void kernel_launch(void* const* d_in, const int* in_sizes, int n_in,
                              void* d_out, int out_size, void* d_ws, size_t ws_size,
                              hipStream_t stream) {
  const float* x   = (const float*)d_in[0];
  const float* Wq  = (const float*)d_in[1];
  const float* Wkv = (const float*)d_in[2];
  const float* Wo  = (const float*)d_in[3];
  const float* bo  = (const float*)d_in[4];
  float* out = (float*)d_out;

  // workspace layout (161 MiB), same as rounds 9/12/14/15:
  //   [0, 32MiB)         xbT
  //   [32MiB, +768KiB)   Wcat
  //   [.., +256KiB)      Wobf
  //   [34603008, +64MiB) kws  (k_attn overwrites in-place with attnout)
  //   [101711872,+64MiB) vws
  // q lives in d_out (64 MiB bf16), dead before final GEMM writes fp32 there.
  char* ws = (char*)d_ws;
  u16* xbT  = (u16*)ws;
  u16* Wcat = (u16*)(ws + 33554432);
  u16* Wobf = (u16*)(ws + 34340864);
  u16* kws  = (u16*)(ws + 34603008);
  u16* vws  = (u16*)(ws + 101711872);
  u16* qws  = (u16*)d_out;

  k_convert_w<<<2048, 256, 0, stream>>>(Wq, Wkv, Wo, Wcat, Wobf);
  k_convert_x<<<1024, 256, 0, stream>>>(x, xbT);
  k_gemm<256, 0><<<6144, 512, 0, stream>>>(Wcat, xbT, qws, kws, vws, nullptr, nullptr);
  k_attn<<<2048, 512, 0, stream>>>(qws, kws, vws, kws);
  k_gemm<512, 1><<<1024, 512, 0, stream>>>(Wobf, kws, nullptr, nullptr, nullptr, out, bo);
}